// Round 2
// baseline (101.628 us; speedup 1.0000x reference)
//
#include <hip/hip_runtime.h>

// Problem constants (from reference setup_inputs)
constexpr int B = 8, C = 3, H = 544, W = 960;
constexpr int KH = 3, KW = 3;
constexpr int HW = H * W;        // 522240
constexpr int WT = 8;            // outputs per thread along W
constexpr int WQ = W / WT;       // 120
constexpr int NK = C * KH * KW;  // 27 filter planes
constexpr int BLOCK = 256;
constexpr int TOTAL = B * H * WQ;    // 522240 threads
constexpr int NBLK = TOTAL / BLOCK;  // 2040 blocks
static_assert(TOTAL % BLOCK == 0, "grid must be exact");
static_assert(NBLK % 8 == 0, "swizzle must be bijective");

__global__ __launch_bounds__(BLOCK) void DynFilter_kernel(
    const float* __restrict__ x,     // [B, C, H, W]
    const float* __restrict__ filt,  // [B, 27, H, W]
    float* __restrict__ out)         // [B, 1, H, W]
{
    // XCD-aware chunked swizzle: HW round-robins blockIdx across 8 XCDs;
    // this remap gives each XCD a contiguous 255-block chunk = one batch
    // image => x rows (h-1,h,h+1) reused within the same per-XCD L2.
    int bid  = (int)blockIdx.x;
    int sbid = (bid & 7) * (NBLK / 8) + (bid >> 3);
    int tid  = sbid * BLOCK + (int)threadIdx.x;

    int wq = tid % WQ;
    int t  = tid / WQ;
    int h  = t % H;
    int b  = t / H;
    int w0 = wq * WT;

    float4 acc0 = make_float4(0.f, 0.f, 0.f, 0.f);
    float4 acc1 = make_float4(0.f, 0.f, 0.f, 0.f);

    const float* fbase = filt + (size_t)b * NK * HW + (size_t)h * W + w0;

    #pragma unroll
    for (int c = 0; c < C; ++c) {
        const float* xc = x + ((size_t)b * C + c) * HW;
        #pragma unroll
        for (int i = 0; i < KH; ++i) {
            int hr = h + i - 1;
            bool vh = (unsigned)hr < (unsigned)H;
            // xv[q] holds x column (w0 - 1 + q), q = 0..9
            float xv[WT + 2];
            if (vh) {
                const float* xr = xc + (size_t)hr * W + w0;  // 16B aligned
                float4 m0 = *reinterpret_cast<const float4*>(xr);
                float4 m1 = *reinterpret_cast<const float4*>(xr + 4);
                xv[1] = m0.x; xv[2] = m0.y; xv[3] = m0.z; xv[4] = m0.w;
                xv[5] = m1.x; xv[6] = m1.y; xv[7] = m1.z; xv[8] = m1.w;
                xv[0] = (w0 > 0)      ? xr[-1] : 0.f;
                xv[9] = (w0 + WT < W) ? xr[WT] : 0.f;
            } else {
                #pragma unroll
                for (int q = 0; q < WT + 2; ++q) xv[q] = 0.f;
            }
            #pragma unroll
            for (int j = 0; j < KW; ++j) {
                int k = c * (KH * KW) + i * KW + j;
                const float* fp = fbase + (size_t)k * HW;
                float4 f0 = *reinterpret_cast<const float4*>(fp);
                float4 f1 = *reinterpret_cast<const float4*>(fp + 4);
                acc0.x += xv[j]     * f0.x;
                acc0.y += xv[j + 1] * f0.y;
                acc0.z += xv[j + 2] * f0.z;
                acc0.w += xv[j + 3] * f0.w;
                acc1.x += xv[j + 4] * f1.x;
                acc1.y += xv[j + 5] * f1.y;
                acc1.z += xv[j + 6] * f1.z;
                acc1.w += xv[j + 7] * f1.w;
            }
        }
    }

    float* op = out + (size_t)b * HW + (size_t)h * W + w0;
    *reinterpret_cast<float4*>(op)     = acc0;
    *reinterpret_cast<float4*>(op + 4) = acc1;
}

extern "C" void kernel_launch(void* const* d_in, const int* in_sizes, int n_in,
                              void* d_out, int out_size, void* d_ws, size_t ws_size,
                              hipStream_t stream) {
    const float* x    = (const float*)d_in[0];
    const float* filt = (const float*)d_in[1];
    float* out        = (float*)d_out;

    DynFilter_kernel<<<NBLK, BLOCK, 0, stream>>>(x, filt, out);
}